// Round 3
// baseline (2438.941 us; speedup 1.0000x reference)
//
#include <hip/hip_runtime.h>
#include <math.h>

#define T_TOTAL   1000
#define CHUNK     50
#define NCHUNK    20
#define BATCH     256
#define NH        256
#define NIN       85

static constexpr float SIGMA_C = 0.15811388300841897f;  // sqrt(2/0.2)*0.05
static constexpr float ALPHA_C = 0.2f;

using half8   = __attribute__((ext_vector_type(8))) _Float16;
using f32x4   = __attribute__((ext_vector_type(4))) float;

// workspace layout
#define GXE_F     ((size_t)(CHUNK+1)*16*48*256)  // f32 gxe: [t][R][tau(48)][lane(64)][4]
#define WPACK_US  (8u*6u*8u*64u*8u)              // recurrent-weight B-fragments (f16 bits)
#define WXPACK_US (48u*3u*64u*8u)                // x-weight B-fragments (K padded 85->96)

__device__ __forceinline__ unsigned short f2h(float f){
  _Float16 h = (_Float16)f;
  return __builtin_bit_cast(unsigned short, h);
}

__device__ __forceinline__ void gload_lds16(const void* g, void* l){
  __builtin_amdgcn_global_load_lds((const __attribute__((address_space(1))) void*)g,
                                   (__attribute__((address_space(3))) void*)l, 16, 0, 0);
}

// ---------------- k0: pack weights into MFMA B-fragment order (f16) ----------------
// wpack[w(8)][tile(6: r0,r1,u0,u1,c0,c1)][kt(8)][lane(64)][j(8)]
//   value = W[k = kt*32 + (l>>4)*8 + j][col = 16*(2w+(tile&1)) + (l&15)]
// wxpack[tau(48)][kt(3)][lane(64)][j(8)]   (k >= 85 zero-padded)
__global__ void k0_pack(const float* __restrict__ gk, const float* __restrict__ ck,
                        unsigned short* __restrict__ wpack, unsigned short* __restrict__ wxpack){
  int tid = blockIdx.x*256 + threadIdx.x;
  if (tid < (int)WPACK_US) {
    int j = tid & 7, l = (tid >> 3) & 63, kt = (tid >> 9) & 7, wt = tid >> 12;
    int w = wt / 6, tile = wt - 6*w;
    int lrow = l & 15, lquad = l >> 4;
    int k = kt*32 + lquad*8 + j;            // hidden index 0..255
    int tau = 2*w + (tile & 1);             // n-tile 0..15
    int kind = tile >> 1;                   // 0=r, 1=u, 2=c
    float v;
    if (kind == 0)      v = gk[(size_t)(85 + k)*512 + 16*tau + lrow];
    else if (kind == 1) v = gk[(size_t)(85 + k)*512 + 256 + 16*tau + lrow];
    else                v = ck[(size_t)(85 + k)*256 + 16*tau + lrow];
    wpack[tid] = f2h(v);
  } else if (tid < (int)(WPACK_US + WXPACK_US)) {
    int f = tid - (int)WPACK_US;
    int j = f & 7, l = (f >> 3) & 63, r = f >> 9;   // r = tau*3 + kt
    int kt = r % 3, tau = r / 3;
    int lrow = l & 15, lquad = l >> 4;
    int k = kt*32 + lquad*8 + j;            // x index, pad >=85 -> 0
    float v = 0.0f;
    if (k < NIN) {
      if (tau < 32) v = gk[(size_t)k*512 + 16*tau + lrow];
      else          v = ck[(size_t)k*256 + 16*(tau-32) + lrow];
    }
    wxpack[f] = f2h(v);
  }
}

// ---------------- k1: gxe precompute (f16 MFMA, K=96 padded, f32 output) ----------------
// gxe[tl][R][tau(48)][lane(64)][i(4)] f32, C-fragment order:
//   tau<32 : gate preact x-part for gate col 16*tau+(l&15), rows b=16R+(l>>4)*4+i
//   tau>=32: E = cand_bias + cx + sigma*noise for cand col 16*(tau-32)+(l&15)
__global__ __launch_bounds__(256) void k1_gxe(const float* __restrict__ x, const float* __restrict__ nz,
                       const float* __restrict__ gb, const float* __restrict__ cb,
                       const unsigned short* __restrict__ wxpack, float* __restrict__ gxe,
                       int t0){
  int R  = blockIdx.x;
  int tl = blockIdx.y;
  int t  = t0 + tl;
  int tid = threadIdx.x;
  __shared__ _Float16 xA[16][104];           // 96 K (padded) + 8 pad
  {
    int r = tid >> 4, c0 = tid & 15;
    const float* xrow = x + ((size_t)t*BATCH + 16*R + r)*NIN;
    for (int c = c0; c < 96; c += 16)
      xA[r][c] = (_Float16)(c < NIN ? xrow[c] : 0.0f);
  }
  __syncthreads();
  int l = tid & 63, wv = tid >> 6;
  int lrow = l & 15, lquad = l >> 4;
  const half8* xA8 = (const half8*)xA;       // row stride 104 f16 = 13 half8
  half8 afr[3];
  #pragma unroll
  for (int kt = 0; kt < 3; ++kt)
    afr[kt] = xA8[lrow*13 + kt*4 + lquad];
  const half8* wx8 = (const half8*)wxpack;
  size_t gbase = ((size_t)tl*16 + R)*48;
  for (int u = 0; u < 12; ++u) {
    int tau = wv + 4*u;                      // balanced: each wave gets 4 cand tiles
    f32x4 acc;
    if (tau < 32) {
      float b = gb[16*tau + lrow];
      acc = (f32x4){b, b, b, b};
    } else {
      int nc = 16*(tau-32) + lrow;
      float b = cb[nc];
      #pragma unroll
      for (int i = 0; i < 4; ++i)
        acc[i] = fmaf(SIGMA_C, nz[((size_t)t*BATCH + 16*R + lquad*4 + i)*NH + nc], b);
    }
    #pragma unroll
    for (int kt = 0; kt < 3; ++kt)
      acc = __builtin_amdgcn_mfma_f32_16x16x32_f16(afr[kt], wx8[((size_t)tau*3 + kt)*64 + l], acc, 0, 0, 0);
    *(f32x4*)(gxe + ((gbase + tau)*64 + (size_t)l)*4) = acc;
  }
}

// ---------------- k2: persistent recurrent scan, 16 WGs x 8 waves ----------------
// WG R owns batch rows [16R,16R+16). Wave w owns n-cols [32w,32w+32).
// Reference semantics: cand = cx + (r .* h) @ Wc_h + sigma*n   (r applied BEFORE matmul!)
// Per step: phase A = h@Wg_h (gate tiles) -> sigmoid -> rh = r.*h published to rhA ->
//           barrier -> phase B = rh@Wc_h -> tanh/leaky update -> hA publish -> barrier.
// Weights VGPR-resident (48 half8/wave). h carried f32 in regs; f16 copies in LDS.
// Gate-x preacts staged via global_load_lds (wave-private gst, lgkmcnt WAR guard);
// E = cx+sigma*n loaded straight to registers (issued early, consumed in ew2).
__global__ __launch_bounds__(512, 2) void k2_rec(const float* __restrict__ hin, float* __restrict__ hst,
                       const unsigned short* __restrict__ wpack,
                       const float* __restrict__ gxe,
                       float* __restrict__ out, int t0){
  int R = blockIdx.x;
  int tid = threadIdx.x;
  int l = tid & 63, w = tid >> 6;
  int lrow = l & 15, lquad = l >> 4;

  __shared__ float    gst[8*4*256];          // [w][gate tile q(4)][lane][4] f32, 32KB
  __shared__ _Float16 hA[16][264];           // h f16  [row][n], stride 264
  __shared__ _Float16 rhA[16][264];          // r.*h f16, same layout

  { // init hA
    int r = tid >> 5, c0 = (tid & 31)*8;
    const float* hrow = hin + ((size_t)(16*R + r))*NH + c0;
    #pragma unroll
    for (int i = 0; i < 8; ++i)
      hA[r][c0+i] = (_Float16)hrow[i];
  }
  float hreg[2][4];                          // h f32, lane-private (rows lquad*4+i, cols 32w+16p+lrow)
  #pragma unroll
  for (int p = 0; p < 2; ++p)
    #pragma unroll
    for (int i = 0; i < 4; ++i)
      hreg[p][i] = hin[(size_t)(16*R + lquad*4 + i)*NH + 32*w + 16*p + lrow];

  // resident weight fragments
  half8 wf[6][8];
  const half8* wp8 = (const half8*)wpack;
  #pragma unroll
  for (int tile = 0; tile < 6; ++tile)
    #pragma unroll
    for (int kt = 0; kt < 8; ++kt)
      wf[tile][kt] = wp8[((w*6 + tile)*8 + kt)*64 + l];

  // gate staging: tile q -> tau = 2w + {0,1,16,17}
  const float* gbase_l = gxe + ((size_t)R*48 + 2*w)*256 + (size_t)l*4;  // per-lane src base
  float* lbase = gst + (size_t)w*4*256;                                  // wave-uniform LDS base
  const size_t gstep = (size_t)16*48*256;                                // floats per time step
  // E tiles: tau = 32+2w, 33+2w  (f32x4 per lane)
  const f32x4* ge = (const f32x4*)gxe + ((size_t)R*48 + 32 + 2*w)*64 + (size_t)l;
  const size_t gstep4 = gstep/4;

  // prologue: stage step 0 gates
  {
    const int tqg[4] = {0, 1, 16, 17};
    #pragma unroll
    for (int q = 0; q < 4; ++q)
      gload_lds16(gbase_l + (size_t)tqg[q]*256, lbase + q*256);
  }
  __syncthreads();

  const half8* hA8  = (const half8*)hA;      // row stride 33 half8
  const half8* rhA8 = (const half8*)rhA;
  const f32x4* sb = (const f32x4*)(gst) + (size_t)w*4*64;
  size_t obase = ((size_t)(16*R + lquad*4))*NH + 32*w + lrow;
  float* outp = out + (size_t)t0*65536;

  for (int t = 0; t < CHUNK; ++t) {
    // consume staged gate preacts (gx incl. gate_bias)
    f32x4 accA[4];
    #pragma unroll
    for (int j = 0; j < 4; ++j) accA[j] = sb[j*64 + l];
    // E(t) straight to regs, issued early, used in ew2
    f32x4 e0 = ge[(size_t)t*gstep4];
    f32x4 e1 = ge[(size_t)t*gstep4 + 64];
    asm volatile("s_waitcnt lgkmcnt(0)" ::: "memory");  // gst reads done before DMA overwrites
    // stage gates for t+1 (wave-private slots; vmcnt drained by end-of-step barrier)
    {
      const int tqg[4] = {0, 1, 16, 17};
      const size_t soff = (size_t)(t+1)*gstep;
      #pragma unroll
      for (int q = 0; q < 4; ++q)
        gload_lds16(gbase_l + soff + (size_t)tqg[q]*256, lbase + q*256);
    }
    // phase A: h @ Wg_h  (tiles r0,r1,u0,u1)
    #pragma unroll
    for (int kt = 0; kt < 8; ++kt){
      half8 af = hA8[lrow*33 + kt*4 + lquad];
      #pragma unroll
      for (int tile = 0; tile < 4; ++tile)
        accA[tile] = __builtin_amdgcn_mfma_f32_16x16x32_f16(af, wf[tile][kt], accA[tile], 0, 0, 0);
    }
    // ew1: gates; publish rh = r .* h
    float aug[2][4];
    #pragma unroll
    for (int p = 0; p < 2; ++p){
      int ncol = 32*w + 16*p + lrow;
      #pragma unroll
      for (int i = 0; i < 4; ++i){
        float er = __expf(-accA[p][i]);
        float rg = __builtin_amdgcn_rcpf(1.0f + er);
        float eu = __expf(-accA[2+p][i]);
        aug[p][i] = ALPHA_C * __builtin_amdgcn_rcpf(1.0f + eu);
        rhA[lquad*4+i][ncol] = (_Float16)(rg * hreg[p][i]);
      }
    }
    __syncthreads();   // rhA visible to all waves
    // phase B: (r.*h) @ Wc_h  (tiles c0,c1)
    f32x4 accB[2];
    accB[0] = (f32x4){0.f,0.f,0.f,0.f};
    accB[1] = (f32x4){0.f,0.f,0.f,0.f};
    #pragma unroll
    for (int kt = 0; kt < 8; ++kt){
      half8 af = rhA8[lrow*33 + kt*4 + lquad];
      #pragma unroll
      for (int tile = 0; tile < 2; ++tile)
        accB[tile] = __builtin_amdgcn_mfma_f32_16x16x32_f16(af, wf[4+tile][kt], accB[tile], 0, 0, 0);
    }
    // ew2: cand -> tanh -> leaky update; publish new h
    #pragma unroll
    for (int p = 0; p < 2; ++p){
      const f32x4 e = p ? e1 : e0;
      int ncol = 32*w + 16*p + lrow;
      #pragma unroll
      for (int i = 0; i < 4; ++i){
        float cand = accB[p][i] + e[i];
        float e2 = __expf(2.0f*cand);
        float c  = (e2 - 1.0f)*__builtin_amdgcn_rcpf(e2 + 1.0f);
        float hold = hreg[p][i];
        float hnew = fmaf(aug[p][i], c - hold, hold);
        hreg[p][i] = hnew;
        hA[lquad*4+i][ncol] = (_Float16)hnew;
        outp[obase + (size_t)i*NH + (size_t)p*16] = hnew;
      }
    }
    outp += 65536;
    __syncthreads(); // hA writes visible before next step's phase A (also drains DMA vmcnt)
  }
  // persist h for next chunk
  #pragma unroll
  for (int p = 0; p < 2; ++p)
    #pragma unroll
    for (int i = 0; i < 4; ++i)
      hst[(size_t)(16*R + lquad*4 + i)*NH + 32*w + 16*p + lrow] = hreg[p][i];
}

extern "C" void kernel_launch(void* const* d_in, const int* in_sizes, int n_in,
                              void* d_out, int out_size, void* d_ws, size_t ws_size,
                              hipStream_t stream) {
  (void)in_sizes; (void)n_in; (void)out_size; (void)ws_size;
  const float* x  = (const float*)d_in[0];
  const float* h0 = (const float*)d_in[1];
  const float* gk = (const float*)d_in[2];
  const float* gb = (const float*)d_in[3];
  const float* ck = (const float*)d_in[4];
  const float* cb = (const float*)d_in[5];
  const float* nz = (const float*)d_in[6];
  float* out = (float*)d_out;

  float* gxe = (float*)d_ws;                 // ~40MB f32
  float* hst = gxe + GXE_F;
  unsigned short* wpack  = (unsigned short*)(hst + 65536);
  unsigned short* wxpack = wpack + WPACK_US;

  k0_pack<<<1056, 256, 0, stream>>>(gk, ck, wpack, wxpack);
  for (int c = 0; c < NCHUNK; ++c) {
    int t0 = c*CHUNK;
    k1_gxe<<<dim3(16, CHUNK), 256, 0, stream>>>(x, nz, gb, cb, wxpack, gxe, t0);
    k2_rec<<<16, 512, 0, stream>>>(c == 0 ? h0 : (const float*)hst, hst, wpack, gxe, out, t0);
  }
}